// Round 4
// baseline (169.513 us; speedup 1.0000x reference)
//
#include <hip/hip_runtime.h>
#include <hip/hip_bf16.h>

#define BB 8
#define SS 4096
#define DD 1024
#define KK 32
#define EE 8
#define PP 4

// ---- output float offsets (tuple concatenated flat, in return order) ----
#define O0 0L                    // expert_weights  (B,S,E)   262144
#define O1 262144L               // expert_indices  (B,S,E)   262144
#define O2 524288L               // phi_weights     (B,S,K)  1048576
#define O3 1572864L              // soft_slots      (B,K*D)   262144
#define O4 1835008L              // expert_inputs   (B,K*D)   262144
#define O5 2097152L              // phi_logits      (B,S,K)  1048576
#define O6 3145728L              // raw_gate_probs  (B,S,K)  1048576

// ---- workspace float offsets ----
#define WA 0L        // softmax partials: 128 blocks * 64 floats
#define WB 8192L     // final m / (1/sum) per (b,k): 8*64 floats
#define WC 16384L    // logits partials (wsP) THEN k_slots partials (reused)

// ============ K1 v2: tiled logits GEMM, LDS-fed register tiles ============
// Grid 512 = 128 token-tiles(256 tok) x 4 d-quarters. Block: 4 waves, each
// wave owns a private 64-d slice + private LDS region (no main-loop barriers).
// Lane tile: 8 tokens x 16 k (acc[8][4] float4 = 128 VGPR). Per 4-d substep:
// 512 FMA vs 16 ds_read_b64(x) + 16 ds_read_b128(w) -> ~80% VALU feed.
__global__ __launch_bounds__(256, 2) void k_logits2(const float* __restrict__ x,
    const float* __restrict__ Wp, float* __restrict__ wsP)
{
    __shared__ float xw[4][256][18];   // pad 18: b64-aligned, 2-way banks (free)
    __shared__ float ww[4][8][36];     // pad 36: b128-aligned, kg-broadcast
    const int tid  = threadIdx.x;
    const int wv   = __builtin_amdgcn_readfirstlane(tid >> 6);
    const int lane = tid & 63;
    const int tg   = lane & 31;        // token group: tokens tg + 32*i
    const int kg   = lane >> 5;        // k half: k in [kg*16, kg*16+16)
    const int blk  = blockIdx.x;
    const int tile = blk >> 2, q = blk & 3;
    const long tok0 = (long)tile * 256;
    const int d0 = q * 256 + wv * 64;  // this wave's 64-d slice

    float4 acc[8][4];
#pragma unroll
    for (int i = 0; i < 8; ++i)
#pragma unroll
        for (int m = 0; m < 4; ++m) acc[i][m] = make_float4(0.f, 0.f, 0.f, 0.f);

    const int sx_t  = lane >> 1;           // x stage: token row 0..31 (+32r)
    const int sx_d  = (lane & 1) * 4;      // x stage: d-quad 0 or 4
    const int sw_d  = lane >> 3;           // w stage: d row 0..7
    const int sw_k  = (lane & 7) * 4;      // w stage: k-quad

    for (int c = 0; c < 8; ++c) {          // 8 chunks of 8 d
        const int db = d0 + c * 8;
        // ---- stage x chunk: 256 tok x 8 d (per-wave private) ----
#pragma unroll
        for (int r = 0; r < 8; ++r) {
            const int t = sx_t + 32 * r;
            const float4 v = *reinterpret_cast<const float4*>(
                x + (tok0 + t) * DD + db + sx_d);
            *reinterpret_cast<float2*>(&xw[wv][t][sx_d])     = make_float2(v.x, v.y);
            *reinterpret_cast<float2*>(&xw[wv][t][sx_d + 2]) = make_float2(v.z, v.w);
        }
        // ---- stage w chunk: 8 d x 32 k ----
        {
            const float4 v = *reinterpret_cast<const float4*>(
                Wp + (long)(db + sw_d) * KK + sw_k);
            *reinterpret_cast<float4*>(&ww[wv][sw_d][sw_k]) = v;
        }
        // ---- compute: 2 substeps x 4 d ----
#pragma unroll
        for (int dl = 0; dl < 8; dl += 4) {
            float2 xa[8], xb[8];
#pragma unroll
            for (int i = 0; i < 8; ++i) {
                const int t = tg + 32 * i;
                xa[i] = *reinterpret_cast<const float2*>(&xw[wv][t][dl]);
                xb[i] = *reinterpret_cast<const float2*>(&xw[wv][t][dl + 2]);
            }
#pragma unroll
            for (int m = 0; m < 4; ++m) {
#pragma unroll
                for (int dd = 0; dd < 4; ++dd) {
                    const float4 wf = *reinterpret_cast<const float4*>(
                        &ww[wv][dl + dd][kg * 16 + m * 4]);
#pragma unroll
                    for (int i = 0; i < 8; ++i) {
                        const float xs = (dd == 0) ? xa[i].x : (dd == 1) ? xa[i].y
                                       : (dd == 2) ? xb[i].x : xb[i].y;
                        acc[i][m].x = fmaf(xs, wf.x, acc[i][m].x);
                        acc[i][m].y = fmaf(xs, wf.y, acc[i][m].y);
                        acc[i][m].z = fmaf(xs, wf.z, acc[i][m].z);
                        acc[i][m].w = fmaf(xs, wf.w, acc[i][m].w);
                    }
                }
            }
        }
    }

    // ---- cross-wave reduce (4 rounds over k-quads m), scratch in xw[wv] ----
    for (int g = 0; g < 4; ++g) {
        if (wv) {
            float* sp = &xw[wv][0][0];     // reused as [64][34] float2-aligned
#pragma unroll
            for (int i = 0; i < 8; ++i) {
                *reinterpret_cast<float2*>(&sp[lane * 34 + i * 4])     =
                    make_float2(acc[i][g].x, acc[i][g].y);
                *reinterpret_cast<float2*>(&sp[lane * 34 + i * 4 + 2]) =
                    make_float2(acc[i][g].z, acc[i][g].w);
            }
        }
        __syncthreads();
        if (wv == 0) {
#pragma unroll
            for (int w2 = 1; w2 < 4; ++w2) {
                const float* sp = &xw[w2][0][0];
#pragma unroll
                for (int i = 0; i < 8; ++i) {
                    const float2 a = *reinterpret_cast<const float2*>(&sp[lane * 34 + i * 4]);
                    const float2 b = *reinterpret_cast<const float2*>(&sp[lane * 34 + i * 4 + 2]);
                    acc[i][g].x += a.x; acc[i][g].y += a.y;
                    acc[i][g].z += b.x; acc[i][g].w += b.y;
                }
            }
        }
        __syncthreads();
    }

    // ---- wave 0 writes block partial: wsP[blk][kq(8)][tok(256)][4] ----
    if (wv == 0) {
        float* base = wsP + (long)blk * (8L * 256 * 4);
#pragma unroll
        for (int i = 0; i < 8; ++i) {
            const int t = tg + 32 * i;
#pragma unroll
            for (int m = 0; m < 4; ++m) {
                const int kq = kg * 4 + m;
                *reinterpret_cast<float4*>(base + ((long)kq * 256 + t) * 4) = acc[i][m];
            }
        }
    }
}

// ============ K1b: combine 4 d-quarter partials + bias + full epilogue =====
__global__ __launch_bounds__(256) void k_comb(const float* __restrict__ wsP,
    const float* __restrict__ bp, float* __restrict__ out)
{
    const int tile = blockIdx.x;          // 128 tiles of 256 tokens
    const int tid  = threadIdx.x;
    const long g   = (long)tile * 256 + tid;
    float acc[KK];
#pragma unroll
    for (int k = 0; k < KK; ++k) acc[k] = bp[k];
#pragma unroll
    for (int q = 0; q < 4; ++q) {
        const float* base = wsP + (long)(tile * 4 + q) * (8L * 256 * 4);
#pragma unroll
        for (int kq = 0; kq < 8; ++kq) {
            const float4 v = *reinterpret_cast<const float4*>(
                base + ((long)kq * 256 + tid) * 4);
            acc[kq * 4]     += v.x;
            acc[kq * 4 + 1] += v.y;
            acc[kq * 4 + 2] += v.z;
            acc[kq * 4 + 3] += v.w;
        }
    }
    float4* pl = reinterpret_cast<float4*>(out + O5 + g * KK);
#pragma unroll
    for (int q = 0; q < 8; ++q)
        pl[q] = make_float4(acc[4*q], acc[4*q+1], acc[4*q+2], acc[4*q+3]);
    float rg[KK];
#pragma unroll
    for (int e = 0; e < EE; ++e) {
        const float m = fmaxf(fmaxf(acc[4*e], acc[4*e+1]), fmaxf(acc[4*e+2], acc[4*e+3]));
        float s = 0.f;
#pragma unroll
        for (int p = 0; p < PP; ++p) { rg[4*e+p] = __expf(acc[4*e+p] - m); s += rg[4*e+p]; }
        const float ri = 1.f / s;
#pragma unroll
        for (int p = 0; p < PP; ++p) rg[4*e+p] *= ri;
    }
    float4* prg = reinterpret_cast<float4*>(out + O6 + g * KK);
#pragma unroll
    for (int q = 0; q < 8; ++q)
        prg[q] = make_float4(rg[4*q], rg[4*q+1], rg[4*q+2], rg[4*q+3]);
    float4* pew = reinterpret_cast<float4*>(out + O0 + g * EE);
    pew[0] = make_float4(0.125f, 0.125f, 0.125f, 0.125f);
    pew[1] = make_float4(0.125f, 0.125f, 0.125f, 0.125f);
    float4* pei = reinterpret_cast<float4*>(out + O1 + g * EE);
    pei[0] = make_float4(0.f, 1.f, 2.f, 3.f);
    pei[1] = make_float4(4.f, 5.f, 6.f, 7.f);
}

// ============ K1 fallback (v1, direct write) if workspace is tiny ==========
__global__ __launch_bounds__(256) void k_logits_fb(const float* __restrict__ x,
    const float* __restrict__ Wp, const float* __restrict__ bp,
    float* __restrict__ out)
{
    __shared__ float red[3][64][KK + 1];
    const int tid  = threadIdx.x;
    const int wv   = __builtin_amdgcn_readfirstlane(tid >> 6);
    const int lane = tid & 63;
    const long g   = (long)blockIdx.x * 64 + lane;
    const float* xrow = x + g * DD + wv * 256;
    const float* wb   = Wp + (long)wv * 256 * KK;
    float acc[KK];
#pragma unroll
    for (int k = 0; k < KK; ++k) acc[k] = 0.f;
#pragma unroll 2
    for (int dq = 0; dq < 256; dq += 4) {
        const float4 xv = *reinterpret_cast<const float4*>(xrow + dq);
        const float* wr = wb + dq * KK;
#pragma unroll
        for (int j = 0; j < 4; ++j) {
            const float xs = (j == 0) ? xv.x : (j == 1) ? xv.y : (j == 2) ? xv.z : xv.w;
#pragma unroll
            for (int k = 0; k < KK; ++k)
                acc[k] = fmaf(xs, wr[j * KK + k], acc[k]);
        }
    }
    if (wv) {
#pragma unroll
        for (int k = 0; k < KK; ++k) red[wv - 1][lane][k] = acc[k];
    }
    __syncthreads();
    if (wv == 0) {
#pragma unroll
        for (int k = 0; k < KK; ++k)
            acc[k] += red[0][lane][k] + red[1][lane][k] + red[2][lane][k] + bp[k];
        float4* pl = reinterpret_cast<float4*>(out + O5 + g * KK);
#pragma unroll
        for (int q = 0; q < 8; ++q)
            pl[q] = make_float4(acc[4*q], acc[4*q+1], acc[4*q+2], acc[4*q+3]);
        float rg[KK];
#pragma unroll
        for (int e = 0; e < EE; ++e) {
            const float m = fmaxf(fmaxf(acc[4*e], acc[4*e+1]), fmaxf(acc[4*e+2], acc[4*e+3]));
            float s = 0.f;
#pragma unroll
            for (int p = 0; p < PP; ++p) { rg[4*e+p] = __expf(acc[4*e+p] - m); s += rg[4*e+p]; }
            const float ri = 1.f / s;
#pragma unroll
            for (int p = 0; p < PP; ++p) rg[4*e+p] *= ri;
        }
        float4* prg = reinterpret_cast<float4*>(out + O6 + g * KK);
#pragma unroll
        for (int q = 0; q < 8; ++q)
            prg[q] = make_float4(rg[4*q], rg[4*q+1], rg[4*q+2], rg[4*q+3]);
        float4* pew = reinterpret_cast<float4*>(out + O0 + g * EE);
        pew[0] = make_float4(0.125f, 0.125f, 0.125f, 0.125f);
        pew[1] = make_float4(0.125f, 0.125f, 0.125f, 0.125f);
        float4* pei = reinterpret_cast<float4*>(out + O1 + g * EE);
        pei[0] = make_float4(0.f, 1.f, 2.f, 3.f);
        pei[1] = make_float4(4.f, 5.f, 6.f, 7.f);
    }
}

// ============ K2a: per-(b, s-chunk) partial max & sum(exp) over 256 rows ====
__global__ __launch_bounds__(256) void k_smpart(const float* __restrict__ out,
                                                float* __restrict__ ws)
{
    const int blk = blockIdx.x;            // b*16 + sc
    const int b = blk >> 4, sc = blk & 15;
    const int tid = threadIdx.x;
    const int wv  = __builtin_amdgcn_readfirstlane(tid >> 6);
    const long s  = (long)sc * 256 + tid;
    const float* row = out + O5 + ((long)b * SS + s) * KK;
    float v[KK];
    const float4* r4 = reinterpret_cast<const float4*>(row);
#pragma unroll
    for (int q = 0; q < 8; ++q) {
        const float4 t = r4[q];
        v[4*q] = t.x; v[4*q+1] = t.y; v[4*q+2] = t.z; v[4*q+3] = t.w;
    }
    float m[KK];
#pragma unroll
    for (int k = 0; k < KK; ++k) m[k] = v[k];
    for (int off = 1; off < 64; off <<= 1) {
#pragma unroll
        for (int k = 0; k < KK; ++k) m[k] = fmaxf(m[k], __shfl_xor(m[k], off));
    }
    __shared__ float lm[4][KK];
    __shared__ float lsum[4][KK];
    if ((tid & 63) == 0) {
#pragma unroll
        for (int k = 0; k < KK; ++k) lm[wv][k] = m[k];
    }
    __syncthreads();
#pragma unroll
    for (int k = 0; k < KK; ++k)
        m[k] = fmaxf(fmaxf(lm[0][k], lm[1][k]), fmaxf(lm[2][k], lm[3][k]));
    float sv[KK];
#pragma unroll
    for (int k = 0; k < KK; ++k) sv[k] = __expf(v[k] - m[k]);
    for (int off = 1; off < 64; off <<= 1) {
#pragma unroll
        for (int k = 0; k < KK; ++k) sv[k] += __shfl_xor(sv[k], off);
    }
    if ((tid & 63) == 0) {
#pragma unroll
        for (int k = 0; k < KK; ++k) lsum[wv][k] = sv[k];
    }
    __syncthreads();
    if (tid == 0) {
#pragma unroll
        for (int k = 0; k < KK; ++k) {
            ws[WA + (long)blk * 64 + k]      = m[k];
            ws[WA + (long)blk * 64 + 32 + k] = lsum[0][k] + lsum[1][k] + lsum[2][k] + lsum[3][k];
        }
    }
}

// ============ K2b: combine 16 chunk stats -> final m, 1/sum per (b,k) ======
__global__ __launch_bounds__(256) void k_smcomb(float* __restrict__ ws)
{
    const int tid = threadIdx.x;           // = b*32 + k  (exactly 256)
    const int b = tid >> 5, k = tid & 31;
    float m = -1e30f, s = 0.f;
    for (int c = 0; c < 16; ++c) {
        const float mc = ws[WA + (long)(b * 16 + c) * 64 + k];
        const float sc = ws[WA + (long)(b * 16 + c) * 64 + 32 + k];
        const float nm = fmaxf(m, mc);
        s = s * __expf(m - nm) + sc * __expf(mc - nm);
        m = nm;
    }
    ws[WB + (long)b * 64 + k]      = m;
    ws[WB + (long)b * 64 + 32 + k] = 1.f / s;
}

// ============ K2c: phi_weights = exp(logit - m) * rinv (elementwise) =======
__global__ __launch_bounds__(256) void k_pw(float* __restrict__ out,
                                            const float* __restrict__ ws)
{
    const long i4 = (long)blockIdx.x * 256 + threadIdx.x;   // < 262144
    const float4 l4 = reinterpret_cast<const float4*>(out + O5)[i4];
    const long idx = i4 * 4;
    const int b  = (int)(idx >> 17);       // / (S*K = 131072)
    const int k0 = (int)(idx & 31);
    const float* mb = ws + WB + (long)b * 64;
    const float lv[4] = {l4.x, l4.y, l4.z, l4.w};
    float r[4];
#pragma unroll
    for (int j = 0; j < 4; ++j) {
        const int k = k0 + j;
        r[j] = __expf(lv[j] - mb[k]) * mb[32 + k];
    }
    reinterpret_cast<float4*>(out + O2)[i4] = make_float4(r[0], r[1], r[2], r[3]);
}

// ============ K3: partial soft_slots[b][k][d] = sum_s pw * x ===============
__global__ __launch_bounds__(256) void k_slots(const float* __restrict__ x,
    const float* __restrict__ out, float* __restrict__ dst, int SC, int SLEN)
{
    const int blk = blockIdx.x;
    const int sc  = blk % SC;
    const int t2  = blk / SC;
    const int dc  = t2 & 3;
    const int b   = t2 >> 2;
    const int d   = dc * 256 + threadIdx.x;
    float acc[KK];
#pragma unroll
    for (int k = 0; k < KK; ++k) acc[k] = 0.f;
    const long s0 = (long)sc * SLEN;
    const float* pw = out + O2 + ((long)b * SS + s0) * KK;
    const float* xp = x + ((long)b * SS + s0) * DD + d;
#pragma unroll 4
    for (int i = 0; i < SLEN; ++i) {
        const float xv = xp[(long)i * DD];
        const float* wr = pw + (long)i * KK;
#pragma unroll
        for (int k = 0; k < KK; ++k) acc[k] = fmaf(wr[k], xv, acc[k]);
    }
    float* o = dst + ((long)(sc * BB + b) * KK) * DD + d;
#pragma unroll
    for (int k = 0; k < KK; ++k) o[(long)k * DD] = acc[k];
}

// ============ K4: reduce SC partials -> soft_slots + expert_inputs =========
__global__ __launch_bounds__(256) void k_red(const float* __restrict__ src,
                                             float* __restrict__ out, int SC)
{
    const long i4 = (long)blockIdx.x * 256 + threadIdx.x;   // < 65536
    float4 s = make_float4(0.f, 0.f, 0.f, 0.f);
    const float4* p = reinterpret_cast<const float4*>(src);
    for (int c = 0; c < SC; ++c) {
        const float4 t = p[(long)c * 65536 + i4];
        s.x += t.x; s.y += t.y; s.z += t.z; s.w += t.w;
    }
    reinterpret_cast<float4*>(out + O3)[i4] = s;
    reinterpret_cast<float4*>(out + O4)[i4] = s;
}

extern "C" void kernel_launch(void* const* d_in, const int* in_sizes, int n_in,
                              void* d_out, int out_size, void* d_ws, size_t ws_size,
                              hipStream_t stream)
{
    const float* x  = (const float*)d_in[0];
    const float* Wp = (const float*)d_in[1];
    const float* bp = (const float*)d_in[2];
    float* out = (float*)d_out;
    float* ws  = (float*)d_ws;

    const size_t wfloats = ws_size / 4;
    const long wsP_floats = 512L * 8 * 256 * 4;   // 4.19M = 16.8 MB

    // ---- logits ----
    if (wfloats >= (size_t)(WC + wsP_floats)) {
        hipLaunchKernelGGL(k_logits2, dim3(512), dim3(256), 0, stream, x, Wp, ws + WC);
        hipLaunchKernelGGL(k_comb,    dim3(128), dim3(256), 0, stream, ws + WC, bp, out);
    } else {
        hipLaunchKernelGGL(k_logits_fb, dim3(512), dim3(256), 0, stream, x, Wp, bp, out);
    }

    // ---- seq-softmax ----
    hipLaunchKernelGGL(k_smpart, dim3(128),  dim3(256), 0, stream, out, ws);
    hipLaunchKernelGGL(k_smcomb, dim3(1),    dim3(256), 0, stream, ws);
    hipLaunchKernelGGL(k_pw,     dim3(1024), dim3(256), 0, stream, out, ws);

    // ---- soft slots (WC region reused after k_comb consumed wsP) ----
    int SC = 0;
    if      (wfloats >= (size_t)(WC + 16L * 262144)) SC = 16;
    else if (wfloats >= (size_t)(WC +  8L * 262144)) SC = 8;
    else if (wfloats >= (size_t)(WC +  4L * 262144)) SC = 4;
    else if (wfloats >= (size_t)(WC +  2L * 262144)) SC = 2;
    else if (wfloats >= (size_t)(WC +  1L * 262144)) SC = 1;

    if (SC >= 1) {
        hipLaunchKernelGGL(k_slots, dim3(BB * 4 * SC), dim3(256), 0, stream,
                           x, out, ws + WC, SC, SS / SC);
        hipLaunchKernelGGL(k_red,   dim3(256), dim3(256), 0, stream, ws + WC, out, SC);
    } else {
        hipLaunchKernelGGL(k_slots, dim3(BB * 4), dim3(256), 0, stream,
                           x, out, out + O3, 1, SS);
        hipLaunchKernelGGL(k_red,   dim3(256), dim3(256), 0, stream, out + O3, out, 1);
    }
}

// Round 5
// 145.284 us; speedup vs baseline: 1.1668x; 1.1668x over previous
//
#include <hip/hip_runtime.h>
#include <hip/hip_bf16.h>

#define BB 8
#define SS 4096
#define DD 1024
#define KK 32
#define EE 8
#define PP 4

// ---- output float offsets (tuple concatenated flat, in return order) ----
#define O0 0L                    // expert_weights  (B,S,E)   262144
#define O1 262144L               // expert_indices  (B,S,E)   262144
#define O2 524288L               // phi_weights     (B,S,K)  1048576
#define O3 1572864L              // soft_slots      (B,K*D)   262144
#define O4 1835008L              // expert_inputs   (B,K*D)   262144
#define O5 2097152L              // phi_logits      (B,S,K)  1048576
#define O6 3145728L              // raw_gate_probs  (B,S,K)  1048576

// ---- workspace float offsets ----
#define WA 0L        // softmax partials: 128 blocks * 64 floats
#define WB 8192L     // final m / (1/sum) per (b,k): 8*64 floats
#define WC 16384L    // k_slots partials: SC * B*K*D floats

// ============ K1 v4: logits GEMM, k-split waves, LDS-staged x & W ==========
// Grid 512 blocks (64 tokens each), block = 4 waves; wave wv owns k-slice
// [8wv, 8wv+8). D iterated in 16 chunks of 64, x(16KB)+W(8KB) double-buffered
// in LDS. Stage loads are full 64B row segments (zero over-fetch). Compute:
// per 4-d quad: 1 ds_read_b128 (x) + 2 broadcast b128 (w) + 32 FMA.
// Epilogue per-wave: O5/O6 k-slice direct, O0 by wave0, O1 by wave1.
__global__ __launch_bounds__(256) void k_logits4(const float* __restrict__ x,
    const float* __restrict__ Wp, const float* __restrict__ bp,
    float* __restrict__ out)
{
    __shared__ float xl[2][64][68];    // [buf][tok][d+pad4]
    __shared__ float wl[2][64][32];    // [buf][d][k]
    const int tid  = threadIdx.x;
    const int wv   = __builtin_amdgcn_readfirstlane(tid >> 6);
    const int lane = tid & 63;
    const long tok0 = (long)blockIdx.x * 64;
    const long g   = tok0 + lane;
    const int sr = tid >> 2;            // stage: row 0..63
    const int sco = (tid & 3) * 4;      // stage: col quad base

    float acc[8];
#pragma unroll
    for (int j = 0; j < 8; ++j) acc[j] = 0.f;

    float4 xr[4], wr[2];
    // ---- preload + write chunk 0 ----
#pragma unroll
    for (int j = 0; j < 4; ++j)
        xr[j] = *reinterpret_cast<const float4*>(x + (tok0 + sr) * DD + sco + j * 16);
#pragma unroll
    for (int j = 0; j < 2; ++j)
        wr[j] = *reinterpret_cast<const float4*>(Wp + tid * 8 + j * 4);
#pragma unroll
    for (int j = 0; j < 4; ++j)
        *reinterpret_cast<float4*>(&xl[0][sr][sco + j * 16]) = xr[j];
#pragma unroll
    for (int j = 0; j < 2; ++j)
        *reinterpret_cast<float4*>(&wl[0][0][0] + tid * 8 + j * 4) = wr[j];
    __syncthreads();

    for (int c = 0; c < 16; ++c) {
        const int cb = c & 1;
        if (c < 15) {
            const long dg = (long)(c + 1) * 64;
#pragma unroll
            for (int j = 0; j < 4; ++j)
                xr[j] = *reinterpret_cast<const float4*>(
                    x + (tok0 + sr) * DD + dg + sco + j * 16);
#pragma unroll
            for (int j = 0; j < 2; ++j)
                wr[j] = *reinterpret_cast<const float4*>(
                    Wp + dg * KK + tid * 8 + j * 4);
        }
        // ---- compute chunk c ----
        const float* xb = &xl[cb][lane][0];
        const float* wb = &wl[cb][0][0] + wv * 8;
#pragma unroll 4
        for (int dq = 0; dq < 16; ++dq) {
            const float4 xv = *reinterpret_cast<const float4*>(xb + dq * 4);
#pragma unroll
            for (int dd = 0; dd < 4; ++dd) {
                const float xs = (dd == 0) ? xv.x : (dd == 1) ? xv.y
                               : (dd == 2) ? xv.z : xv.w;
                const float4 w0 = *reinterpret_cast<const float4*>(wb + (dq * 4 + dd) * 32);
                const float4 w1 = *reinterpret_cast<const float4*>(wb + (dq * 4 + dd) * 32 + 4);
                acc[0] = fmaf(xs, w0.x, acc[0]);
                acc[1] = fmaf(xs, w0.y, acc[1]);
                acc[2] = fmaf(xs, w0.z, acc[2]);
                acc[3] = fmaf(xs, w0.w, acc[3]);
                acc[4] = fmaf(xs, w1.x, acc[4]);
                acc[5] = fmaf(xs, w1.y, acc[5]);
                acc[6] = fmaf(xs, w1.z, acc[6]);
                acc[7] = fmaf(xs, w1.w, acc[7]);
            }
        }
        if (c < 15) {
#pragma unroll
            for (int j = 0; j < 4; ++j)
                *reinterpret_cast<float4*>(&xl[cb ^ 1][sr][sco + j * 16]) = xr[j];
#pragma unroll
            for (int j = 0; j < 2; ++j)
                *reinterpret_cast<float4*>(&wl[cb ^ 1][0][0] + tid * 8 + j * 4) = wr[j];
        }
        __syncthreads();
    }

    // ---- epilogue: bias, O5, raw-gate (experts 2wv, 2wv+1), consts ----
#pragma unroll
    for (int j = 0; j < 8; ++j) acc[j] += bp[wv * 8 + j];
    float* o5 = out + O5 + g * KK + wv * 8;
    *reinterpret_cast<float4*>(o5)     = make_float4(acc[0], acc[1], acc[2], acc[3]);
    *reinterpret_cast<float4*>(o5 + 4) = make_float4(acc[4], acc[5], acc[6], acc[7]);
    float rg[8];
#pragma unroll
    for (int e = 0; e < 2; ++e) {
        const float* a = &acc[e * 4];
        const float m = fmaxf(fmaxf(a[0], a[1]), fmaxf(a[2], a[3]));
        float s = 0.f;
#pragma unroll
        for (int p = 0; p < PP; ++p) { rg[e*4+p] = __expf(a[p] - m); s += rg[e*4+p]; }
        const float ri = 1.f / s;
#pragma unroll
        for (int p = 0; p < PP; ++p) rg[e*4+p] *= ri;
    }
    float* o6 = out + O6 + g * KK + wv * 8;
    *reinterpret_cast<float4*>(o6)     = make_float4(rg[0], rg[1], rg[2], rg[3]);
    *reinterpret_cast<float4*>(o6 + 4) = make_float4(rg[4], rg[5], rg[6], rg[7]);
    if (wv == 0) {
        float4* p = reinterpret_cast<float4*>(out + O0 + g * EE);
        p[0] = make_float4(0.125f, 0.125f, 0.125f, 0.125f);
        p[1] = make_float4(0.125f, 0.125f, 0.125f, 0.125f);
    } else if (wv == 1) {
        float4* p = reinterpret_cast<float4*>(out + O1 + g * EE);
        p[0] = make_float4(0.f, 1.f, 2.f, 3.f);
        p[1] = make_float4(4.f, 5.f, 6.f, 7.f);
    }
}

// ============ K2a: per-(b, s-chunk) partial max & sum(exp) over 256 rows ====
__global__ __launch_bounds__(256) void k_smpart(const float* __restrict__ out,
                                                float* __restrict__ ws)
{
    const int blk = blockIdx.x;            // b*16 + sc
    const int b = blk >> 4, sc = blk & 15;
    const int tid = threadIdx.x;
    const int wv  = __builtin_amdgcn_readfirstlane(tid >> 6);
    const long s  = (long)sc * 256 + tid;
    const float* row = out + O5 + ((long)b * SS + s) * KK;
    float v[KK];
    const float4* r4 = reinterpret_cast<const float4*>(row);
#pragma unroll
    for (int q = 0; q < 8; ++q) {
        const float4 t = r4[q];
        v[4*q] = t.x; v[4*q+1] = t.y; v[4*q+2] = t.z; v[4*q+3] = t.w;
    }
    float m[KK];
#pragma unroll
    for (int k = 0; k < KK; ++k) m[k] = v[k];
    for (int off = 1; off < 64; off <<= 1) {
#pragma unroll
        for (int k = 0; k < KK; ++k) m[k] = fmaxf(m[k], __shfl_xor(m[k], off));
    }
    __shared__ float lm[4][KK];
    __shared__ float lsum[4][KK];
    if ((tid & 63) == 0) {
#pragma unroll
        for (int k = 0; k < KK; ++k) lm[wv][k] = m[k];
    }
    __syncthreads();
#pragma unroll
    for (int k = 0; k < KK; ++k)
        m[k] = fmaxf(fmaxf(lm[0][k], lm[1][k]), fmaxf(lm[2][k], lm[3][k]));
    float sv[KK];
#pragma unroll
    for (int k = 0; k < KK; ++k) sv[k] = __expf(v[k] - m[k]);
    for (int off = 1; off < 64; off <<= 1) {
#pragma unroll
        for (int k = 0; k < KK; ++k) sv[k] += __shfl_xor(sv[k], off);
    }
    if ((tid & 63) == 0) {
#pragma unroll
        for (int k = 0; k < KK; ++k) lsum[wv][k] = sv[k];
    }
    __syncthreads();
    if (tid == 0) {
#pragma unroll
        for (int k = 0; k < KK; ++k) {
            ws[WA + (long)blk * 64 + k]      = m[k];
            ws[WA + (long)blk * 64 + 32 + k] = lsum[0][k] + lsum[1][k] + lsum[2][k] + lsum[3][k];
        }
    }
}

// ============ K2b: combine 16 chunk stats -> final m, 1/sum per (b,k) ======
__global__ __launch_bounds__(256) void k_smcomb(float* __restrict__ ws)
{
    const int tid = threadIdx.x;           // = b*32 + k  (exactly 256)
    const int b = tid >> 5, k = tid & 31;
    float m = -1e30f, s = 0.f;
    for (int c = 0; c < 16; ++c) {
        const float mc = ws[WA + (long)(b * 16 + c) * 64 + k];
        const float sc = ws[WA + (long)(b * 16 + c) * 64 + 32 + k];
        const float nm = fmaxf(m, mc);
        s = s * __expf(m - nm) + sc * __expf(mc - nm);
        m = nm;
    }
    ws[WB + (long)b * 64 + k]      = m;
    ws[WB + (long)b * 64 + 32 + k] = 1.f / s;
}

// ============ K2c: phi_weights = exp(logit - m) * rinv (elementwise) =======
__global__ __launch_bounds__(256) void k_pw(float* __restrict__ out,
                                            const float* __restrict__ ws)
{
    const long i4 = (long)blockIdx.x * 256 + threadIdx.x;   // < 262144
    const float4 l4 = reinterpret_cast<const float4*>(out + O5)[i4];
    const long idx = i4 * 4;
    const int b  = (int)(idx >> 17);       // / (S*K = 131072)
    const int k0 = (int)(idx & 31);
    const float* mb = ws + WB + (long)b * 64;
    const float lv[4] = {l4.x, l4.y, l4.z, l4.w};
    float r[4];
#pragma unroll
    for (int j = 0; j < 4; ++j) {
        const int k = k0 + j;
        r[j] = __expf(lv[j] - mb[k]) * mb[32 + k];
    }
    reinterpret_cast<float4*>(out + O2)[i4] = make_float4(r[0], r[1], r[2], r[3]);
}

// ============ K3 v2: soft_slots partials, pw staged in LDS ================
// blocks = B*4*SC; thread owns one d column, acc[32]; s iterated in chunks
// of 64 with pw (8KB) double-buffered in LDS, read as wave broadcasts.
__global__ __launch_bounds__(256) void k_slots2(const float* __restrict__ x,
    const float* __restrict__ out, float* __restrict__ dst, int SC, int SLEN)
{
    __shared__ float pwl[2][64 * KK];
    const int tid = threadIdx.x;
    const int blk = blockIdx.x;
    const int sc  = blk % SC;
    const int t2  = blk / SC;
    const int dc  = t2 & 3;
    const int b   = t2 >> 2;
    const int d   = dc * 256 + tid;
    float acc[KK];
#pragma unroll
    for (int k = 0; k < KK; ++k) acc[k] = 0.f;
    const long s0 = (long)sc * SLEN;
    const float* pw = out + O2 + ((long)b * SS + s0) * KK;
    const float* xp = x + ((long)b * SS + s0) * DD + d;
    const int NCH = SLEN >> 6;

    float4 r0 = *reinterpret_cast<const float4*>(pw + tid * 8);
    float4 r1 = *reinterpret_cast<const float4*>(pw + tid * 8 + 4);
    *reinterpret_cast<float4*>(&pwl[0][tid * 8])     = r0;
    *reinterpret_cast<float4*>(&pwl[0][tid * 8 + 4]) = r1;
    __syncthreads();

    for (int ch = 0; ch < NCH; ++ch) {
        const int cb = ch & 1;
        if (ch + 1 < NCH) {
            const float* pn = pw + (long)(ch + 1) * 64 * KK;
            r0 = *reinterpret_cast<const float4*>(pn + tid * 8);
            r1 = *reinterpret_cast<const float4*>(pn + tid * 8 + 4);
        }
        const float* xc = xp + (long)ch * 64 * DD;
        const float* pb = &pwl[cb][0];
#pragma unroll 8
        for (int i = 0; i < 64; ++i) {
            const float xv = xc[(long)i * DD];
#pragma unroll
            for (int q = 0; q < 8; ++q) {
                const float4 w = *reinterpret_cast<const float4*>(pb + i * KK + q * 4);
                acc[4*q]   = fmaf(w.x, xv, acc[4*q]);
                acc[4*q+1] = fmaf(w.y, xv, acc[4*q+1]);
                acc[4*q+2] = fmaf(w.z, xv, acc[4*q+2]);
                acc[4*q+3] = fmaf(w.w, xv, acc[4*q+3]);
            }
        }
        if (ch + 1 < NCH) {
            *reinterpret_cast<float4*>(&pwl[cb ^ 1][tid * 8])     = r0;
            *reinterpret_cast<float4*>(&pwl[cb ^ 1][tid * 8 + 4]) = r1;
        }
        __syncthreads();
    }
    float* o = dst + ((long)(sc * BB + b) * KK) * DD + d;
#pragma unroll
    for (int k = 0; k < KK; ++k) o[(long)k * DD] = acc[k];
}

// ============ K4: reduce SC partials -> soft_slots + expert_inputs =========
__global__ __launch_bounds__(256) void k_red(const float* __restrict__ src,
                                             float* __restrict__ out, int SC)
{
    const long i4 = (long)blockIdx.x * 256 + threadIdx.x;   // < 65536
    float4 s = make_float4(0.f, 0.f, 0.f, 0.f);
    const float4* p = reinterpret_cast<const float4*>(src);
    for (int c = 0; c < SC; ++c) {
        const float4 t = p[(long)c * 65536 + i4];
        s.x += t.x; s.y += t.y; s.z += t.z; s.w += t.w;
    }
    reinterpret_cast<float4*>(out + O3)[i4] = s;
    reinterpret_cast<float4*>(out + O4)[i4] = s;
}

extern "C" void kernel_launch(void* const* d_in, const int* in_sizes, int n_in,
                              void* d_out, int out_size, void* d_ws, size_t ws_size,
                              hipStream_t stream)
{
    const float* x  = (const float*)d_in[0];
    const float* Wp = (const float*)d_in[1];
    const float* bp = (const float*)d_in[2];
    float* out = (float*)d_out;
    float* ws  = (float*)d_ws;

    const size_t wfloats = ws_size / 4;

    hipLaunchKernelGGL(k_logits4, dim3(512),  dim3(256), 0, stream, x, Wp, bp, out);
    hipLaunchKernelGGL(k_smpart,  dim3(128),  dim3(256), 0, stream, out, ws);
    hipLaunchKernelGGL(k_smcomb,  dim3(1),    dim3(256), 0, stream, ws);
    hipLaunchKernelGGL(k_pw,      dim3(1024), dim3(256), 0, stream, out, ws);

    int SC = 0;
    if      (wfloats >= (size_t)(WC + 16L * 262144)) SC = 16;
    else if (wfloats >= (size_t)(WC +  8L * 262144)) SC = 8;
    else if (wfloats >= (size_t)(WC +  4L * 262144)) SC = 4;
    else if (wfloats >= (size_t)(WC +  2L * 262144)) SC = 2;
    else if (wfloats >= (size_t)(WC +  1L * 262144)) SC = 1;

    if (SC >= 1) {
        hipLaunchKernelGGL(k_slots2, dim3(BB * 4 * SC), dim3(256), 0, stream,
                           x, out, ws + WC, SC, SS / SC);
        hipLaunchKernelGGL(k_red,    dim3(256), dim3(256), 0, stream, ws + WC, out, SC);
    } else {
        hipLaunchKernelGGL(k_slots2, dim3(BB * 4), dim3(256), 0, stream,
                           x, out, out + O3, 1, SS);
        hipLaunchKernelGGL(k_red,    dim3(256), dim3(256), 0, stream, out + O3, out, 1);
    }
}